// Round 15
// baseline (193.294 us; speedup 1.0000x reference)
//
#include <hip/hip_runtime.h>
#include <math.h>

typedef float  f32x4 __attribute__((ext_vector_type(4)));
typedef float  f32x2 __attribute__((ext_vector_type(2)));
typedef __bf16 bf16x8 __attribute__((ext_vector_type(8)));
typedef unsigned short u16x8 __attribute__((ext_vector_type(8)));
typedef unsigned short u16x4 __attribute__((ext_vector_type(4)));

#define DEVI __device__ __forceinline__

constexpr int Bc = 4, Tc = 2048, Cc = 1024, Hc = 16, HSc = 64;
constexpr int Mc  = Bc * Tc;    // 8192 rows
constexpr int N1c = 3 * Cc;     // 3072 qkv cols
constexpr int Kc  = Cc;         // 1024 reduce dim

DEVI unsigned short f2bf(float f) {            // RNE fp32 -> bf16
    unsigned u = __builtin_bit_cast(unsigned, f);
    u += 0x7FFFu + ((u >> 16) & 1u);
    return (unsigned short)(u >> 16);
}
DEVI float bf2f(unsigned short s) {
    unsigned u = ((unsigned)s) << 16;
    return __builtin_bit_cast(float, u);
}

typedef const __attribute__((address_space(1))) void* gbl_vp;
typedef __attribute__((address_space(3))) void* lds_vp;
DEVI void gload16(const unsigned short* g, unsigned short* l) {
    __builtin_amdgcn_global_load_lds((gbl_vp)g, (lds_vp)l, 16, 0, 0);
}

// ---------------------------------------------------------------------------
// Prep 0: RoPE table  tab[t][d] = (cos(t*theta_d), sin(t*theta_d)), d=0..31
// ---------------------------------------------------------------------------
__global__ void rope_tab_kernel(f32x2* __restrict__ tab)
{
    const int i = blockIdx.x * blockDim.x + threadIdx.x;   // 0 .. 2048*32
    const int t = i >> 5, d = i & 31;
    float theta = exp2f(-(float)d * 0.41524101186186f);    // 10000^(-d/32)
    float s, c;
    sincosf((float)t * theta, &s, &c);
    f32x2 v; v[0] = c; v[1] = s;
    tab[i] = v;
}

// ---------------------------------------------------------------------------
// Prep 1: fp32 -> bf16 elementwise (x). 8 elems/thread.
// ---------------------------------------------------------------------------
__global__ void cvt_kernel(const float* __restrict__ in,
                           unsigned short* __restrict__ out)
{
    const size_t i = ((size_t)blockIdx.x * blockDim.x + threadIdx.x) * 8;
    f32x4 a = *reinterpret_cast<const f32x4*>(in + i);
    f32x4 b = *reinterpret_cast<const f32x4*>(in + i + 4);
    u16x8 o;
    o[0] = f2bf(a[0]); o[1] = f2bf(a[1]); o[2] = f2bf(a[2]); o[3] = f2bf(a[3]);
    o[4] = f2bf(b[0]); o[5] = f2bf(b[1]); o[6] = f2bf(b[2]); o[7] = f2bf(b[3]);
    *reinterpret_cast<u16x8*>(out + i) = o;
}

// ---------------------------------------------------------------------------
// Prep 2: W [K][N] fp32 -> Wt [N][K] bf16 (transpose + convert), 64x64 tiles.
// ---------------------------------------------------------------------------
__global__ void wt_kernel(const float* __restrict__ W,
                          unsigned short* __restrict__ Wt, int N, int K)
{
    __shared__ unsigned short Ts[64][72];
    const int tid = threadIdx.x;
    const int n0 = blockIdx.x * 64, k0 = blockIdx.y * 64;

    #pragma unroll
    for (int i = 0; i < 4; ++i) {
        int kr = (tid >> 4) + i * 16, nc = (tid & 15) * 4;
        f32x4 v = *reinterpret_cast<const f32x4*>(W + (size_t)(k0 + kr) * N + n0 + nc);
        #pragma unroll
        for (int e = 0; e < 4; ++e) Ts[kr][nc + e] = f2bf(v[e]);
    }
    __syncthreads();
    #pragma unroll
    for (int i = 0; i < 2; ++i) {
        int s = tid * 2 + i;
        int n = s >> 3, k8 = (s & 7) * 8;
        u16x8 o;
        #pragma unroll
        for (int j = 0; j < 8; ++j) o[j] = Ts[k8 + j][n];
        *reinterpret_cast<u16x8*>(Wt + (size_t)(n0 + n) * K + k0 + k8) = o;
    }
}

// ---------------------------------------------------------------------------
// bf16 GEMM (R14 proven): C = A @ Bt^T + bias
// 128x128 tile, BK=64, 256 thr = 4 waves; global_load_lds w=16 staging,
// pre-swizzled source + XOR ds_read (0 conflicts), XCD m-slice L2 mapping.
// MODE 0: Q -> RoPE * softmax-scale; K -> RoPE; V -> LDS-transposed
//         coalesced 16B stores.
// MODE 1: fp32 + bias to f_out.
// ---------------------------------------------------------------------------
template <int MODE, int NCOLS>
__global__ void gemm_kernel(const unsigned short* __restrict__ A,
                            const unsigned short* __restrict__ Bt,
                            const float* __restrict__ bias,
                            const f32x2* __restrict__ rope_t,
                            unsigned short* __restrict__ q_out,
                            unsigned short* __restrict__ k_out,
                            unsigned short* __restrict__ v_out,
                            float* __restrict__ f_out)
{
    __shared__ unsigned short SM[2 * 128 * 64];   // As | Bs ; reused as Tv
    unsigned short* As = SM;
    unsigned short* Bs = SM + 128 * 64;

    const int tid  = threadIdx.x;
    const int lane = tid & 63, wid = tid >> 6;
    const int wr = wid >> 1, wc = wid & 1;
    const int lrow = lane & 15, lk = lane >> 4;

    // L2-locality mapping: xcd owns 8 m-tiles x all n-tiles.
    const int xcd = blockIdx.x & 7, loc = blockIdx.x >> 3;
    const int m0 = (xcd * 8 + (loc & 7)) * 128;
    const int n0 = (loc >> 3) * 128;

    f32x4 acc[4][4] = {};

    for (int kt = 0; kt < Kc / 64; ++kt) {
        const int k0 = kt * 64;
        #pragma unroll
        for (int i = 0; i < 4; ++i) {
            const int s   = ((i * 4 + wid) << 6) + lane;
            const int row = s >> 3;
            const int gc  = (s & 7) ^ (row & 7);
            gload16(A  + (size_t)(m0 + row) * Kc + k0 + gc * 8, &As[(i * 4 + wid) << 9]);
            gload16(Bt + (size_t)(n0 + row) * Kc + k0 + gc * 8, &Bs[(i * 4 + wid) << 9]);
        }
        __syncthreads();

        #pragma unroll
        for (int kk = 0; kk < 2; ++kk) {
            bf16x8 a[4], b[4];
            #pragma unroll
            for (int mt = 0; mt < 4; ++mt) {
                const int ra = wr * 64 + mt * 16 + lrow;
                a[mt] = __builtin_bit_cast(bf16x8,
                    *reinterpret_cast<const u16x8*>(&As[ra * 64 + (((kk * 4 + lk) ^ (ra & 7)) << 3)]));
            }
            #pragma unroll
            for (int nt = 0; nt < 4; ++nt) {
                const int rb = wc * 64 + nt * 16 + lrow;
                b[nt] = __builtin_bit_cast(bf16x8,
                    *reinterpret_cast<const u16x8*>(&Bs[rb * 64 + (((kk * 4 + lk) ^ (rb & 7)) << 3)]));
            }
            #pragma unroll
            for (int mt = 0; mt < 4; ++mt)
                #pragma unroll
                for (int nt = 0; nt < 4; ++nt)
                    acc[mt][nt] = __builtin_amdgcn_mfma_f32_16x16x32_bf16(a[mt], b[nt], acc[mt][nt], 0, 0, 0);
        }
        __syncthreads();
    }

    // ---- epilogue ----
    if constexpr (MODE == 1) {
        #pragma unroll
        for (int mt = 0; mt < 4; ++mt)
            #pragma unroll
            for (int nt = 0; nt < 4; ++nt)
                #pragma unroll
                for (int r = 0; r < 4; ++r) {
                    int grow = m0 + wr * 64 + mt * 16 + lk * 4 + r;
                    int gcol = n0 + wc * 64 + nt * 16 + lrow;
                    f_out[(size_t)grow * Cc + gcol] = acc[mt][nt][r] + bias[gcol];
                }
    } else if (n0 >= 2 * Cc) {
        // ---- V: transpose via LDS (stride 136, 16B-aligned rows), 2 passes
        unsigned short* Tv = SM;                  // 64 x 136 u16 = 17.4 KB
        const int bb = m0 >> 11, t0 = m0 & (Tc - 1);
        #pragma unroll
        for (int p = 0; p < 2; ++p) {
            if (wc == p) {
                #pragma unroll
                for (int mt = 0; mt < 4; ++mt)
                    #pragma unroll
                    for (int nt = 0; nt < 4; ++nt)
                        #pragma unroll
                        for (int r = 0; r < 4; ++r) {
                            int hs_l = nt * 16 + lrow;
                            int t_l  = wr * 64 + mt * 16 + lk * 4 + r;
                            int gcol = n0 + wc * 64 + nt * 16 + lrow;
                            Tv[hs_l * 136 + t_l] = f2bf(acc[mt][nt][r] + bias[gcol]);
                        }
            }
            __syncthreads();
            const int h  = ((n0 - 2 * Cc) >> 6) + p;     // head 0..15
            const int bh = bb * Hc + h;
            #pragma unroll
            for (int i = 0; i < 4; ++i) {
                int ch = i * 256 + tid;                  // 0..1023 chunks of 8
                int hs = ch >> 4, tc = ch & 15;
                u16x8 v = *reinterpret_cast<const u16x8*>(&Tv[hs * 136 + tc * 8]);
                *reinterpret_cast<u16x8*>(
                    &v_out[((size_t)bh * HSc + hs) * Tc + t0 + tc * 8]) = v;
            }
            __syncthreads();
        }
    } else {
        // ---- Q/K: fused table-RoPE scatter; Q pre-scaled by 0.125*log2(e)
        const bool isQ = (n0 < Cc);
        unsigned short* dst = isQ ? q_out : k_out;
        const float oscale = isQ ? 0.18033688011112042f : 1.0f;
        #pragma unroll
        for (int mt = 0; mt < 4; ++mt)
            #pragma unroll
            for (int nt = 0; nt < 4; ++nt)
                #pragma unroll
                for (int r = 0; r < 4; ++r) {
                    int grow = m0 + wr * 64 + mt * 16 + lk * 4 + r;
                    int gcol = n0 + wc * 64 + nt * 16 + lrow;
                    float val = acc[mt][nt][r] + bias[gcol];
                    int cc   = gcol & (Cc - 1);
                    int h    = cc >> 6, hs = cc & 63;
                    int bb   = grow >> 11, t = grow & (Tc - 1);
                    int bh   = bb * Hc + h;
                    float partner = __shfl_xor(val, 1, 64);
                    const bool ev = !(lrow & 1);
                    float x1 = ev ? val : partner;
                    float x2 = ev ? partner : val;
                    int d = hs >> 1;
                    f32x2 cs = rope_t[t * 32 + d];
                    float o = ev ? (x1 * cs[0] - x2 * cs[1])
                                 : (x1 * cs[1] + x2 * cs[0]);
                    int hs_out = ev ? d : d + 32;
                    dst[((size_t)bh * Tc + t) * HSc + hs_out] = f2bf(o * oscale);
                }
    }
}

// ---------------------------------------------------------------------------
// Causal flash attention v9: wave = 64 q-rows (f=4) -> each K/V LDS fragment
// read feeds 4 MFMAs (LDS bytes/q-row 750->500). Block = 4 waves = 256 rows;
// grid = 64 bh x 8 superblocks (XCD-local LPT), 2 blocks/CU.
// No-max softmax is element-independent: exp2+lsum+P-store run per-ct right
// after QK MFMA (S register footprint stays 4 x f32x4). dbuf + vmcnt(4),
// diagonal-only masking, deferred row-sum.
// ---------------------------------------------------------------------------
__launch_bounds__(256, 2)
__global__ void attn_kernel(const unsigned short* __restrict__ Q,
                            const unsigned short* __restrict__ K,
                            const unsigned short* __restrict__ Vt,
                            unsigned short* __restrict__ O)
{
    constexpr int PST = 72;
    __shared__ unsigned short Ks[2][64 * 64];
    __shared__ unsigned short Vs[2][64 * 64];
    __shared__ unsigned short Pl[4 * 64 * PST];   // 64 P-rows per wave

    const int tid = threadIdx.x, lane = tid & 63, wid = tid >> 6;
    const int lrow = lane & 15, lk = lane >> 4;

    const int xcd = blockIdx.x & 7, loc = blockIdx.x >> 3;   // loc 0..63
    const int bh  = xcd * 8 + (loc & 7);
    const int qs  = 7 - (loc >> 3);                          // heavy first
    const int b = bh >> 4, h = bh & 15;

    const unsigned short* Qb = Q  + (size_t)bh * Tc  * HSc;
    const unsigned short* Kb = K  + (size_t)bh * Tc  * HSc;
    const unsigned short* Vb = Vt + (size_t)bh * HSc * Tc;
    unsigned short* pl = &Pl[wid * 64 * PST];

    auto stage = [&](int buf, int kt) {      // 4 gloads/thread
        const int kv0 = kt * 64;
        #pragma unroll
        for (int rr = 0; rr < 2; ++rr) {
            const int s   = ((rr * 4 + wid) << 6) + lane;
            const int row = s >> 3;
            const int gc  = (s & 7) ^ (row & 7);
            gload16(Kb + (size_t)(kv0 + row) * HSc + gc * 8, &Ks[buf][(rr * 4 + wid) << 9]);
            gload16(Vb + (size_t)row * Tc + kv0 + gc * 8,    &Vs[buf][(rr * 4 + wid) << 9]);
        }
    };

    const int wq0 = qs * 256 + wid * 64;      // this wave's first q row
    const int ntile = 4 * qs + 4;

    // hoist Q fragments (64 x 64: 4 frag-rows); Q arrives pre-scaled
    bf16x8 qf[4][2];
    #pragma unroll
    for (int f = 0; f < 4; ++f)
        #pragma unroll
        for (int ks = 0; ks < 2; ++ks)
            qf[f][ks] = __builtin_bit_cast(bf16x8,
                *reinterpret_cast<const u16x8*>(Qb + (size_t)(wq0 + f * 16 + lrow) * HSc + ks * 32 + lk * 8));

    f32x4 Oacc[4][4] = {};
    float lsum[4][4] = {};

    stage(0, 0);
    for (int kt = 0; kt < ntile; ++kt) {
        const int kv0 = kt * 64;
        const int cur = kt & 1;
        const bool pre = (kt + 1 < ntile);
        if (pre) stage(cur ^ 1, kt + 1);
        if (pre) asm volatile("s_waitcnt vmcnt(4)" ::: "memory");
        else     asm volatile("s_waitcnt vmcnt(0)" ::: "memory");
        __builtin_amdgcn_s_barrier();

        if (kv0 <= wq0 + 63) {                // wave-uniform: any live kv?
            const bool dtile = (kv0 + 63 > wq0);   // tile touches diagonal
            // ---- per-ct: QK MFMA (K frag shared over 4 f) -> exp2 -> P store
            #pragma unroll
            for (int ct = 0; ct < 4; ++ct) {
                const int ro = ct * 16 + lrow;
                bf16x8 kf[2];
                #pragma unroll
                for (int ks = 0; ks < 2; ++ks)
                    kf[ks] = __builtin_bit_cast(bf16x8,
                        *reinterpret_cast<const u16x8*>(&Ks[cur][ro * 64 + (((ks * 4 + lk) ^ (ro & 7)) << 3)]));
                f32x4 S[4] = {};
                #pragma unroll
                for (int f = 0; f < 4; ++f)
                    #pragma unroll
                    for (int ks = 0; ks < 2; ++ks)
                        S[f] = __builtin_amdgcn_mfma_f32_16x16x32_bf16(qf[f][ks], kf[ks], S[f], 0, 0, 0);

                if (dtile) {
                    #pragma unroll
                    for (int f = 0; f < 4; ++f)
                        #pragma unroll
                        for (int r = 0; r < 4; ++r) {
                            float s = S[f][r];
                            if (kv0 + ct * 16 + lrow > wq0 + f * 16 + lk * 4 + r) s = -1e30f;
                            float pv = __builtin_amdgcn_exp2f(s);
                            lsum[f][r] += pv;
                            pl[(f * 16 + lk * 4 + r) * PST + ct * 16 + lrow] =
                                __builtin_bit_cast(unsigned short, (__bf16)pv);
                        }
                } else {
                    #pragma unroll
                    for (int f = 0; f < 4; ++f)
                        #pragma unroll
                        for (int r = 0; r < 4; ++r) {
                            float pv = __builtin_amdgcn_exp2f(S[f][r]);
                            lsum[f][r] += pv;
                            pl[(f * 16 + lk * 4 + r) * PST + ct * 16 + lrow] =
                                __builtin_bit_cast(unsigned short, (__bf16)pv);
                        }
                }
            }
            asm volatile("s_waitcnt lgkmcnt(0)" ::: "memory");
            __builtin_amdgcn_sched_barrier(0);
            bf16x8 pf[4][2];
            #pragma unroll
            for (int f = 0; f < 4; ++f)
                #pragma unroll
                for (int ks = 0; ks < 2; ++ks)
                    pf[f][ks] = __builtin_bit_cast(bf16x8,
                        *reinterpret_cast<const u16x8*>(&pl[(f * 16 + lrow) * PST + ks * 32 + lk * 8]));

            // ---- O += P V; V frag shared across 4 f
            #pragma unroll
            for (int nt = 0; nt < 4; ++nt) {
                const int ro = nt * 16 + lrow;
                bf16x8 vf[2];
                #pragma unroll
                for (int ks = 0; ks < 2; ++ks)
                    vf[ks] = __builtin_bit_cast(bf16x8,
                        *reinterpret_cast<const u16x8*>(&Vs[cur][ro * 64 + (((ks * 4 + lk) ^ (ro & 7)) << 3)]));
                #pragma unroll
                for (int f = 0; f < 4; ++f)
                    #pragma unroll
                    for (int ks = 0; ks < 2; ++ks)
                        Oacc[f][nt] = __builtin_amdgcn_mfma_f32_16x16x32_bf16(pf[f][ks], vf[ks], Oacc[f][nt], 0, 0, 0);
            }
        }
        asm volatile("s_waitcnt lgkmcnt(0)" ::: "memory");   // all LDS reads landed
        __builtin_amdgcn_sched_barrier(0);
        __builtin_amdgcn_s_barrier();         // safe to overwrite bufs
    }

    // ---- deferred row-sum reduce + store
    #pragma unroll
    for (int f = 0; f < 4; ++f) {
        #pragma unroll
        for (int mk = 1; mk < 16; mk <<= 1)
            #pragma unroll
            for (int r = 0; r < 4; ++r) lsum[f][r] += __shfl_xor(lsum[f][r], mk, 64);
        #pragma unroll
        for (int r = 0; r < 4; ++r) {
            float inv = 1.0f / lsum[f][r];
            int t = wq0 + f * 16 + lk * 4 + r;
            #pragma unroll
            for (int nt = 0; nt < 4; ++nt) {
                int col = h * 64 + nt * 16 + lrow;
                O[((size_t)b * Tc + t) * Cc + col] = f2bf(Oacc[f][nt][r] * inv);
            }
        }
    }
}

// ---------------------------------------------------------------------------
extern "C" void kernel_launch(void* const* d_in, const int* in_sizes, int n_in,
                              void* d_out, int out_size, void* d_ws, size_t ws_size,
                              hipStream_t stream)
{
    const float* x    = (const float*)d_in[0];
    const float* Wqkv = (const float*)d_in[1];
    const float* bqkv = (const float*)d_in[2];
    const float* Wo   = (const float*)d_in[3];
    const float* bo   = (const float*)d_in[4];
    float* out = (float*)d_out;

    char* ws = (char*)d_ws;
    size_t off = 0;
    auto alloc = [&](size_t bytes) {
        void* p = ws + off;
        off += (bytes + 255) & ~(size_t)255;
        return p;
    };
    const size_t elems = (size_t)Bc * Hc * Tc * HSc;          // 8.4M
    unsigned short* Qb  = (unsigned short*)alloc(elems * 2);
    unsigned short* Kb  = (unsigned short*)alloc(elems * 2);
    unsigned short* Vt  = (unsigned short*)alloc(elems * 2);
    unsigned short* Oa  = (unsigned short*)alloc(elems * 2);
    unsigned short* Xb  = (unsigned short*)alloc((size_t)Mc * Kc * 2);      // x bf16
    unsigned short* Wq_t = (unsigned short*)alloc((size_t)N1c * Kc * 2);    // Wqkv^T bf16
    unsigned short* Wo_t = (unsigned short*)alloc((size_t)Cc * Kc * 2);     // Wo^T bf16
    f32x2* Rt = (f32x2*)alloc((size_t)Tc * 32 * 8);                          // rope table

    rope_tab_kernel<<<(Tc * 32) / 256, 256, 0, stream>>>(Rt);
    cvt_kernel<<<(Mc * Kc) / (256 * 8), 256, 0, stream>>>(x, Xb);
    wt_kernel<<<dim3(N1c / 64, Kc / 64), 256, 0, stream>>>(Wqkv, Wq_t, N1c, Kc);
    wt_kernel<<<dim3(Cc / 64, Kc / 64), 256, 0, stream>>>(Wo, Wo_t, Cc, Kc);

    // 1) QKV projection + fused table-RoPE (Q pre-scaled) + coalesced-V scatter
    gemm_kernel<0, N1c><<<(N1c / 128) * (Mc / 128), 256, 0, stream>>>(
        Xb, Wq_t, bqkv, Rt, Qb, Kb, Vt, nullptr);
    // 2) causal flash attention (512 blocks, XCD-local LPT, 64 rows/wave)
    attn_kernel<<<512, 256, 0, stream>>>(Qb, Kb, Vt, Oa);
    // 3) output projection -> fp32 d_out (grid 512)
    gemm_kernel<1, Cc><<<(Cc / 128) * (Mc / 128), 256, 0, stream>>>(
        Oa, Wo_t, bo, nullptr, nullptr, nullptr, nullptr, out);
}

// Round 16
// 185.676 us; speedup vs baseline: 1.0410x; 1.0410x over previous
//
#include <hip/hip_runtime.h>
#include <math.h>

typedef float  f32x4 __attribute__((ext_vector_type(4)));
typedef float  f32x2 __attribute__((ext_vector_type(2)));
typedef __bf16 bf16x8 __attribute__((ext_vector_type(8)));
typedef __bf16 bf16x2 __attribute__((ext_vector_type(2)));
typedef unsigned short u16x8 __attribute__((ext_vector_type(8)));
typedef unsigned int   u32x4 __attribute__((ext_vector_type(4)));

#define DEVI __device__ __forceinline__

constexpr int Bc = 4, Tc = 2048, Cc = 1024, Hc = 16, HSc = 64;
constexpr int Mc  = Bc * Tc;    // 8192 rows
constexpr int N1c = 3 * Cc;     // 3072 qkv cols
constexpr int Kc  = Cc;         // 1024 reduce dim

DEVI unsigned short f2bf(float f) {            // RNE fp32 -> bf16
    unsigned u = __builtin_bit_cast(unsigned, f);
    u += 0x7FFFu + ((u >> 16) & 1u);
    return (unsigned short)(u >> 16);
}

typedef const __attribute__((address_space(1))) void* gbl_vp;
typedef __attribute__((address_space(3))) void* lds_vp;
DEVI void gload16(const unsigned short* g, unsigned short* l) {
    __builtin_amdgcn_global_load_lds((gbl_vp)g, (lds_vp)l, 16, 0, 0);
}

// ---------------------------------------------------------------------------
// Prep 0: RoPE table  tab[t][d] = (cos(t*theta_d), sin(t*theta_d)), d=0..31
// ---------------------------------------------------------------------------
__global__ void rope_tab_kernel(f32x2* __restrict__ tab)
{
    const int i = blockIdx.x * blockDim.x + threadIdx.x;   // 0 .. 2048*32
    const int t = i >> 5, d = i & 31;
    float theta = exp2f(-(float)d * 0.41524101186186f);    // 10000^(-d/32)
    float s, c;
    sincosf((float)t * theta, &s, &c);
    f32x2 v; v[0] = c; v[1] = s;
    tab[i] = v;
}

// ---------------------------------------------------------------------------
// Prep 1: fp32 -> bf16 elementwise (x). 8 elems/thread.
// ---------------------------------------------------------------------------
__global__ void cvt_kernel(const float* __restrict__ in,
                           unsigned short* __restrict__ out)
{
    const size_t i = ((size_t)blockIdx.x * blockDim.x + threadIdx.x) * 8;
    f32x4 a = *reinterpret_cast<const f32x4*>(in + i);
    f32x4 b = *reinterpret_cast<const f32x4*>(in + i + 4);
    u16x8 o;
    o[0] = f2bf(a[0]); o[1] = f2bf(a[1]); o[2] = f2bf(a[2]); o[3] = f2bf(a[3]);
    o[4] = f2bf(b[0]); o[5] = f2bf(b[1]); o[6] = f2bf(b[2]); o[7] = f2bf(b[3]);
    *reinterpret_cast<u16x8*>(out + i) = o;
}

// ---------------------------------------------------------------------------
// Prep 2: W [K][N] fp32 -> Wt [N][K] bf16 (transpose + convert), 64x64 tiles.
// ---------------------------------------------------------------------------
__global__ void wt_kernel(const float* __restrict__ W,
                          unsigned short* __restrict__ Wt, int N, int K)
{
    __shared__ unsigned short Ts[64][72];
    const int tid = threadIdx.x;
    const int n0 = blockIdx.x * 64, k0 = blockIdx.y * 64;

    #pragma unroll
    for (int i = 0; i < 4; ++i) {
        int kr = (tid >> 4) + i * 16, nc = (tid & 15) * 4;
        f32x4 v = *reinterpret_cast<const f32x4*>(W + (size_t)(k0 + kr) * N + n0 + nc);
        #pragma unroll
        for (int e = 0; e < 4; ++e) Ts[kr][nc + e] = f2bf(v[e]);
    }
    __syncthreads();
    #pragma unroll
    for (int i = 0; i < 2; ++i) {
        int s = tid * 2 + i;
        int n = s >> 3, k8 = (s & 7) * 8;
        u16x8 o;
        #pragma unroll
        for (int j = 0; j < 8; ++j) o[j] = Ts[k8 + j][n];
        *reinterpret_cast<u16x8*>(Wt + (size_t)(n0 + n) * K + k0 + k8) = o;
    }
}

// ---------------------------------------------------------------------------
// bf16 GEMM (R14 proven): C = A @ Bt^T + bias
// 128x128 tile, BK=64, 256 thr = 4 waves; global_load_lds w=16 staging,
// pre-swizzled source + XOR ds_read (0 conflicts), XCD m-slice L2 mapping.
// MODE 0: Q -> RoPE * softmax-scale; K -> RoPE; V -> LDS-transposed
//         coalesced 16B stores.
// MODE 1: fp32 + bias to f_out.
// ---------------------------------------------------------------------------
template <int MODE, int NCOLS>
__global__ void gemm_kernel(const unsigned short* __restrict__ A,
                            const unsigned short* __restrict__ Bt,
                            const float* __restrict__ bias,
                            const f32x2* __restrict__ rope_t,
                            unsigned short* __restrict__ q_out,
                            unsigned short* __restrict__ k_out,
                            unsigned short* __restrict__ v_out,
                            float* __restrict__ f_out)
{
    __shared__ unsigned short SM[2 * 128 * 64];   // As | Bs ; reused as Tv
    unsigned short* As = SM;
    unsigned short* Bs = SM + 128 * 64;

    const int tid  = threadIdx.x;
    const int lane = tid & 63, wid = tid >> 6;
    const int wr = wid >> 1, wc = wid & 1;
    const int lrow = lane & 15, lk = lane >> 4;

    // L2-locality mapping: xcd owns 8 m-tiles x all n-tiles.
    const int xcd = blockIdx.x & 7, loc = blockIdx.x >> 3;
    const int m0 = (xcd * 8 + (loc & 7)) * 128;
    const int n0 = (loc >> 3) * 128;

    f32x4 acc[4][4] = {};

    for (int kt = 0; kt < Kc / 64; ++kt) {
        const int k0 = kt * 64;
        #pragma unroll
        for (int i = 0; i < 4; ++i) {
            const int s   = ((i * 4 + wid) << 6) + lane;
            const int row = s >> 3;
            const int gc  = (s & 7) ^ (row & 7);
            gload16(A  + (size_t)(m0 + row) * Kc + k0 + gc * 8, &As[(i * 4 + wid) << 9]);
            gload16(Bt + (size_t)(n0 + row) * Kc + k0 + gc * 8, &Bs[(i * 4 + wid) << 9]);
        }
        __syncthreads();

        #pragma unroll
        for (int kk = 0; kk < 2; ++kk) {
            bf16x8 a[4], b[4];
            #pragma unroll
            for (int mt = 0; mt < 4; ++mt) {
                const int ra = wr * 64 + mt * 16 + lrow;
                a[mt] = __builtin_bit_cast(bf16x8,
                    *reinterpret_cast<const u16x8*>(&As[ra * 64 + (((kk * 4 + lk) ^ (ra & 7)) << 3)]));
            }
            #pragma unroll
            for (int nt = 0; nt < 4; ++nt) {
                const int rb = wc * 64 + nt * 16 + lrow;
                b[nt] = __builtin_bit_cast(bf16x8,
                    *reinterpret_cast<const u16x8*>(&Bs[rb * 64 + (((kk * 4 + lk) ^ (rb & 7)) << 3)]));
            }
            #pragma unroll
            for (int mt = 0; mt < 4; ++mt)
                #pragma unroll
                for (int nt = 0; nt < 4; ++nt)
                    acc[mt][nt] = __builtin_amdgcn_mfma_f32_16x16x32_bf16(a[mt], b[nt], acc[mt][nt], 0, 0, 0);
        }
        __syncthreads();
    }

    // ---- epilogue ----
    if constexpr (MODE == 1) {
        #pragma unroll
        for (int mt = 0; mt < 4; ++mt)
            #pragma unroll
            for (int nt = 0; nt < 4; ++nt)
                #pragma unroll
                for (int r = 0; r < 4; ++r) {
                    int grow = m0 + wr * 64 + mt * 16 + lk * 4 + r;
                    int gcol = n0 + wc * 64 + nt * 16 + lrow;
                    f_out[(size_t)grow * Cc + gcol] = acc[mt][nt][r] + bias[gcol];
                }
    } else if (n0 >= 2 * Cc) {
        // ---- V: transpose via LDS (stride 136, 16B-aligned rows), 2 passes
        unsigned short* Tv = SM;                  // 64 x 136 u16 = 17.4 KB
        const int bb = m0 >> 11, t0 = m0 & (Tc - 1);
        #pragma unroll
        for (int p = 0; p < 2; ++p) {
            if (wc == p) {
                #pragma unroll
                for (int mt = 0; mt < 4; ++mt)
                    #pragma unroll
                    for (int nt = 0; nt < 4; ++nt)
                        #pragma unroll
                        for (int r = 0; r < 4; ++r) {
                            int hs_l = nt * 16 + lrow;
                            int t_l  = wr * 64 + mt * 16 + lk * 4 + r;
                            int gcol = n0 + wc * 64 + nt * 16 + lrow;
                            Tv[hs_l * 136 + t_l] = f2bf(acc[mt][nt][r] + bias[gcol]);
                        }
            }
            __syncthreads();
            const int h  = ((n0 - 2 * Cc) >> 6) + p;     // head 0..15
            const int bh = bb * Hc + h;
            #pragma unroll
            for (int i = 0; i < 4; ++i) {
                int ch = i * 256 + tid;                  // 0..1023 chunks of 8
                int hs = ch >> 4, tc = ch & 15;
                u16x8 v = *reinterpret_cast<const u16x8*>(&Tv[hs * 136 + tc * 8]);
                *reinterpret_cast<u16x8*>(
                    &v_out[((size_t)bh * HSc + hs) * Tc + t0 + tc * 8]) = v;
            }
            __syncthreads();
        }
    } else {
        // ---- Q/K: fused table-RoPE scatter; Q pre-scaled by 0.125*log2(e)
        const bool isQ = (n0 < Cc);
        unsigned short* dst = isQ ? q_out : k_out;
        const float oscale = isQ ? 0.18033688011112042f : 1.0f;
        #pragma unroll
        for (int mt = 0; mt < 4; ++mt)
            #pragma unroll
            for (int nt = 0; nt < 4; ++nt)
                #pragma unroll
                for (int r = 0; r < 4; ++r) {
                    int grow = m0 + wr * 64 + mt * 16 + lk * 4 + r;
                    int gcol = n0 + wc * 64 + nt * 16 + lrow;
                    float val = acc[mt][nt][r] + bias[gcol];
                    int cc   = gcol & (Cc - 1);
                    int h    = cc >> 6, hs = cc & 63;
                    int bb   = grow >> 11, t = grow & (Tc - 1);
                    int bh   = bb * Hc + h;
                    float partner = __shfl_xor(val, 1, 64);
                    const bool ev = !(lrow & 1);
                    float x1 = ev ? val : partner;
                    float x2 = ev ? partner : val;
                    int d = hs >> 1;
                    f32x2 cs = rope_t[t * 32 + d];
                    float o = ev ? (x1 * cs[0] - x2 * cs[1])
                                 : (x1 * cs[1] + x2 * cs[0]);
                    int hs_out = ev ? d : d + 32;
                    dst[((size_t)bh * Tc + t) * HSc + hs_out] = f2bf(o * oscale);
                }
    }
}

// ---------------------------------------------------------------------------
// Causal flash attention v10: v8 geometry (wave = 32 q-rows, block = 128,
// grid 1024 XCD-local LPT) + SWAPPED QK^T (S^T = mfma(kf,qf)) so each lane
// holds a lane-local q-row slice of P. P -> PV A-fragment via in-register
// shfl redistribution (8 shfl + 4 select per (f,ks)); NO P LDS buffer, no
// lgkm drains in the softmax path. Row-sum = 1 scalar/lane + 2 shfl_xor.
// LDS = 32 KB (K/V dbuf only) -> 4 blocks/CU.
// ---------------------------------------------------------------------------
__launch_bounds__(256, 4)
__global__ void attn_kernel(const unsigned short* __restrict__ Q,
                            const unsigned short* __restrict__ K,
                            const unsigned short* __restrict__ Vt,
                            unsigned short* __restrict__ O)
{
    __shared__ unsigned short Ks[2][64 * 64];
    __shared__ unsigned short Vs[2][64 * 64];

    const int tid = threadIdx.x, lane = tid & 63, wid = tid >> 6;
    const int lrow = lane & 15, lk = lane >> 4;

    const int xcd = blockIdx.x & 7, loc = blockIdx.x >> 3;
    const int bh  = xcd * 8 + (loc & 7);
    const int qs  = 15 - (loc >> 3);
    const int b = bh >> 4, h = bh & 15;

    const unsigned short* Qb = Q  + (size_t)bh * Tc  * HSc;
    const unsigned short* Kb = K  + (size_t)bh * Tc  * HSc;
    const unsigned short* Vb = Vt + (size_t)bh * HSc * Tc;

    auto stage = [&](int buf, int kt) {
        const int kv0 = kt * 64;
        #pragma unroll
        for (int rr = 0; rr < 2; ++rr) {
            const int s   = ((rr * 4 + wid) << 6) + lane;
            const int row = s >> 3;
            const int gc  = (s & 7) ^ (row & 7);
            gload16(Kb + (size_t)(kv0 + row) * HSc + gc * 8, &Ks[buf][(rr * 4 + wid) << 9]);
            gload16(Vb + (size_t)row * Tc + kv0 + gc * 8,    &Vs[buf][(rr * 4 + wid) << 9]);
        }
    };

    const int wq0 = qs * 128 + wid * 32;
    const int ntile = 2 * qs + 2;

    // Q fragments (q = wq0 + f*16 + lrow row-local; Q arrives pre-scaled)
    bf16x8 qf[2][2];
    #pragma unroll
    for (int f = 0; f < 2; ++f)
        #pragma unroll
        for (int ks = 0; ks < 2; ++ks)
            qf[f][ks] = __builtin_bit_cast(bf16x8,
                *reinterpret_cast<const u16x8*>(Qb + (size_t)(wq0 + f * 16 + lrow) * HSc + ks * 32 + lk * 8));

    f32x4 Oacc[2][4] = {};
    float lsum[2] = {0.f, 0.f};

    const int sA = lrow + ((lane >> 4 & 1) << 5);   // lrow + 32*(lk&1)
    const int sB = sA + 16;

    stage(0, 0);
    for (int kt = 0; kt < ntile; ++kt) {
        const int kv0 = kt * 64;
        const int cur = kt & 1;
        const bool pre = (kt + 1 < ntile);
        if (pre) stage(cur ^ 1, kt + 1);
        if (pre) asm volatile("s_waitcnt vmcnt(4)" ::: "memory");
        else     asm volatile("s_waitcnt vmcnt(0)" ::: "memory");
        __builtin_amdgcn_s_barrier();

        if (kv0 <= wq0 + 31) {
            // ---- S^T = mfma(kf, qf): lane holds P[q=lrow(+f*16)][kv=ct*16+4lk+r]
            unsigned pk[2][4][2];                 // [f][ct][lo/hi] bf16 pairs
            #pragma unroll
            for (int ct = 0; ct < 4; ++ct) {
                const int ro = ct * 16 + lrow;
                bf16x8 kf[2];
                #pragma unroll
                for (int ks = 0; ks < 2; ++ks)
                    kf[ks] = __builtin_bit_cast(bf16x8,
                        *reinterpret_cast<const u16x8*>(&Ks[cur][ro * 64 + (((ks * 4 + lk) ^ (ro & 7)) << 3)]));
                #pragma unroll
                for (int f = 0; f < 2; ++f) {
                    f32x4 S = {};
                    #pragma unroll
                    for (int ks = 0; ks < 2; ++ks)
                        S = __builtin_amdgcn_mfma_f32_16x16x32_bf16(kf[ks], qf[f][ks], S, 0, 0, 0);
                    const bool mf = (kv0 + 63 > wq0 + f * 16);
                    float pv[4];
                    #pragma unroll
                    for (int r = 0; r < 4; ++r) {
                        float s = S[r];
                        if (mf && (kv0 + ct * 16 + 4 * lk + r > wq0 + f * 16 + lrow)) s = -1e30f;
                        pv[r] = __builtin_amdgcn_exp2f(s);
                        lsum[f] += pv[r];
                    }
                    bf16x2 t0; t0[0] = (__bf16)pv[0]; t0[1] = (__bf16)pv[1];
                    bf16x2 t1; t1[0] = (__bf16)pv[2]; t1[1] = (__bf16)pv[3];
                    pk[f][ct][0] = __builtin_bit_cast(unsigned, t0);
                    pk[f][ct][1] = __builtin_bit_cast(unsigned, t1);
                }
            }

            // ---- assemble PV A-fragments in-register (8 shfl + 4 sel each)
            const bool up = (lk >> 1);
            bf16x8 pf[2][2];
            #pragma unroll
            for (int f = 0; f < 2; ++f)
                #pragma unroll
                for (int ks = 0; ks < 2; ++ks) {
                    u32x4 w;
                    unsigned a0 = __shfl(pk[f][2 * ks][0],     sA, 64);
                    unsigned b0 = __shfl(pk[f][2 * ks + 1][0], sA, 64);
                    unsigned a1 = __shfl(pk[f][2 * ks][1],     sA, 64);
                    unsigned b1 = __shfl(pk[f][2 * ks + 1][1], sA, 64);
                    unsigned a2 = __shfl(pk[f][2 * ks][0],     sB, 64);
                    unsigned b2 = __shfl(pk[f][2 * ks + 1][0], sB, 64);
                    unsigned a3 = __shfl(pk[f][2 * ks][1],     sB, 64);
                    unsigned b3 = __shfl(pk[f][2 * ks + 1][1], sB, 64);
                    w[0] = up ? b0 : a0;
                    w[1] = up ? b1 : a1;
                    w[2] = up ? b2 : a2;
                    w[3] = up ? b3 : a3;
                    pf[f][ks] = __builtin_bit_cast(bf16x8, w);
                }

            // ---- O += P V; V frag shared across both f
            #pragma unroll
            for (int nt = 0; nt < 4; ++nt) {
                const int ro = nt * 16 + lrow;
                bf16x8 vf[2];
                #pragma unroll
                for (int ks = 0; ks < 2; ++ks)
                    vf[ks] = __builtin_bit_cast(bf16x8,
                        *reinterpret_cast<const u16x8*>(&Vs[cur][ro * 64 + (((ks * 4 + lk) ^ (ro & 7)) << 3)]));
                #pragma unroll
                for (int f = 0; f < 2; ++f)
                    #pragma unroll
                    for (int ks = 0; ks < 2; ++ks)
                        Oacc[f][nt] = __builtin_amdgcn_mfma_f32_16x16x32_bf16(pf[f][ks], vf[ks], Oacc[f][nt], 0, 0, 0);
            }
        }
        asm volatile("s_waitcnt lgkmcnt(0)" ::: "memory");   // K/V reads landed
        __builtin_amdgcn_sched_barrier(0);
        __builtin_amdgcn_s_barrier();         // safe to overwrite bufs
    }

    // ---- row-sum finalize: lsum[f] is per-(lane,q=lrow) partial over its kv
    #pragma unroll
    for (int f = 0; f < 2; ++f) {
        float ls = lsum[f];
        ls += __shfl_xor(ls, 16, 64);
        ls += __shfl_xor(ls, 32, 64);
        #pragma unroll
        for (int r = 0; r < 4; ++r) {
            float lr = __shfl(ls, lk * 4 + r, 64);   // lane with lrow = lk*4+r
            float inv = 1.0f / lr;
            int t = wq0 + f * 16 + lk * 4 + r;
            #pragma unroll
            for (int nt = 0; nt < 4; ++nt) {
                int col = h * 64 + nt * 16 + lrow;
                O[((size_t)b * Tc + t) * Cc + col] = f2bf(Oacc[f][nt][r] * inv);
            }
        }
    }
}

// ---------------------------------------------------------------------------
extern "C" void kernel_launch(void* const* d_in, const int* in_sizes, int n_in,
                              void* d_out, int out_size, void* d_ws, size_t ws_size,
                              hipStream_t stream)
{
    const float* x    = (const float*)d_in[0];
    const float* Wqkv = (const float*)d_in[1];
    const float* bqkv = (const float*)d_in[2];
    const float* Wo   = (const float*)d_in[3];
    const float* bo   = (const float*)d_in[4];
    float* out = (float*)d_out;

    char* ws = (char*)d_ws;
    size_t off = 0;
    auto alloc = [&](size_t bytes) {
        void* p = ws + off;
        off += (bytes + 255) & ~(size_t)255;
        return p;
    };
    const size_t elems = (size_t)Bc * Hc * Tc * HSc;          // 8.4M
    unsigned short* Qb  = (unsigned short*)alloc(elems * 2);
    unsigned short* Kb  = (unsigned short*)alloc(elems * 2);
    unsigned short* Vt  = (unsigned short*)alloc(elems * 2);
    unsigned short* Oa  = (unsigned short*)alloc(elems * 2);
    unsigned short* Xb  = (unsigned short*)alloc((size_t)Mc * Kc * 2);      // x bf16
    unsigned short* Wq_t = (unsigned short*)alloc((size_t)N1c * Kc * 2);    // Wqkv^T bf16
    unsigned short* Wo_t = (unsigned short*)alloc((size_t)Cc * Kc * 2);     // Wo^T bf16
    f32x2* Rt = (f32x2*)alloc((size_t)Tc * 32 * 8);                          // rope table

    rope_tab_kernel<<<(Tc * 32) / 256, 256, 0, stream>>>(Rt);
    cvt_kernel<<<(Mc * Kc) / (256 * 8), 256, 0, stream>>>(x, Xb);
    wt_kernel<<<dim3(N1c / 64, Kc / 64), 256, 0, stream>>>(Wqkv, Wq_t, N1c, Kc);
    wt_kernel<<<dim3(Cc / 64, Kc / 64), 256, 0, stream>>>(Wo, Wo_t, Cc, Kc);

    // 1) QKV projection + fused table-RoPE (Q pre-scaled) + coalesced-V scatter
    gemm_kernel<0, N1c><<<(N1c / 128) * (Mc / 128), 256, 0, stream>>>(
        Xb, Wq_t, bqkv, Rt, Qb, Kb, Vt, nullptr);
    // 2) causal flash attention (1024 blocks, XCD-local LPT, in-register P)
    attn_kernel<<<1024, 256, 0, stream>>>(Qb, Kb, Vt, Oa);
    // 3) output projection -> fp32 d_out (grid 512)
    gemm_kernel<1, Cc><<<(Cc / 128) * (Mc / 128), 256, 0, stream>>>(
        Oa, Wo_t, bo, nullptr, nullptr, nullptr, nullptr, out);
}

// Round 17
// 165.216 us; speedup vs baseline: 1.1700x; 1.1238x over previous
//
#include <hip/hip_runtime.h>
#include <math.h>

typedef float  f32x4 __attribute__((ext_vector_type(4)));
typedef float  f32x2 __attribute__((ext_vector_type(2)));
typedef __bf16 bf16x8 __attribute__((ext_vector_type(8)));
typedef unsigned short u16x8 __attribute__((ext_vector_type(8)));

#define DEVI __device__ __forceinline__

constexpr int Bc = 4, Tc = 2048, Cc = 1024, Hc = 16, HSc = 64;
constexpr int Mc  = Bc * Tc;    // 8192 rows
constexpr int N1c = 3 * Cc;     // 3072 qkv cols
constexpr int Kc  = Cc;         // 1024 reduce dim

DEVI unsigned short f2bf(float f) {            // RNE fp32 -> bf16
    unsigned u = __builtin_bit_cast(unsigned, f);
    u += 0x7FFFu + ((u >> 16) & 1u);
    return (unsigned short)(u >> 16);
}

typedef const __attribute__((address_space(1))) void* gbl_vp;
typedef __attribute__((address_space(3))) void* lds_vp;
DEVI void gload16(const unsigned short* g, unsigned short* l) {
    __builtin_amdgcn_global_load_lds((gbl_vp)g, (lds_vp)l, 16, 0, 0);
}

// ---------------------------------------------------------------------------
// Prep A (fused): blocks [0,256) -> RoPE table; blocks [256,4352) -> x cvt.
// ---------------------------------------------------------------------------
__global__ void prep_kernel(const float* __restrict__ x,
                            unsigned short* __restrict__ Xb,
                            f32x2* __restrict__ tab)
{
    const int bid = blockIdx.x;
    if (bid < 256) {
        const int i = bid * 256 + threadIdx.x;   // 0 .. 2048*32
        const int t = i >> 5, d = i & 31;
        float theta = exp2f(-(float)d * 0.41524101186186f);  // 10000^(-d/32)
        float s, c;
        sincosf((float)t * theta, &s, &c);
        f32x2 v; v[0] = c; v[1] = s;
        tab[i] = v;
    } else {
        const size_t i = ((size_t)(bid - 256) * 256 + threadIdx.x) * 8;
        f32x4 a = *reinterpret_cast<const f32x4*>(x + i);
        f32x4 b = *reinterpret_cast<const f32x4*>(x + i + 4);
        u16x8 o;
        o[0] = f2bf(a[0]); o[1] = f2bf(a[1]); o[2] = f2bf(a[2]); o[3] = f2bf(a[3]);
        o[4] = f2bf(b[0]); o[5] = f2bf(b[1]); o[6] = f2bf(b[2]); o[7] = f2bf(b[3]);
        *reinterpret_cast<u16x8*>(Xb + i) = o;
    }
}

// ---------------------------------------------------------------------------
// Prep B (fused): W transposes. blocks [0,768) -> Wqkv (48x16 tiles);
// blocks [768,1024) -> Wo (16x16 tiles). [K][N] fp32 -> [N][K] bf16.
// ---------------------------------------------------------------------------
__global__ void wt2_kernel(const float* __restrict__ Wq,
                           const float* __restrict__ Wo,
                           unsigned short* __restrict__ Wq_t,
                           unsigned short* __restrict__ Wo_t)
{
    __shared__ unsigned short Ts[64][72];
    const int tid = threadIdx.x;

    int bid = blockIdx.x;
    const float* W; unsigned short* Wt; int N, bx, by;
    if (bid < 768) { W = Wq; Wt = Wq_t; N = N1c; bx = bid % 48; by = bid / 48; }
    else { bid -= 768; W = Wo; Wt = Wo_t; N = Cc; bx = bid % 16; by = bid / 16; }
    const int n0 = bx * 64, k0 = by * 64;

    #pragma unroll
    for (int i = 0; i < 4; ++i) {
        int kr = (tid >> 4) + i * 16, nc = (tid & 15) * 4;
        f32x4 v = *reinterpret_cast<const f32x4*>(W + (size_t)(k0 + kr) * N + n0 + nc);
        #pragma unroll
        for (int e = 0; e < 4; ++e) Ts[kr][nc + e] = f2bf(v[e]);
    }
    __syncthreads();
    #pragma unroll
    for (int i = 0; i < 2; ++i) {
        int s = tid * 2 + i;
        int n = s >> 3, k8 = (s & 7) * 8;
        u16x8 o;
        #pragma unroll
        for (int j = 0; j < 8; ++j) o[j] = Ts[k8 + j][n];
        *reinterpret_cast<u16x8*>(Wt + (size_t)(n0 + n) * Kc + k0 + k8) = o;
    }
}

// ---------------------------------------------------------------------------
// bf16 GEMM (R14 proven): C = A @ Bt^T + bias
// 128x128 tile, BK=64, 256 thr = 4 waves; global_load_lds w=16 staging,
// pre-swizzled source + XOR ds_read (0 conflicts), XCD m-slice L2 mapping.
// MODE 0: Q -> RoPE * softmax-scale; K -> RoPE; V -> LDS-transposed
//         coalesced 16B stores.
// MODE 1: fp32 + bias to f_out.
// ---------------------------------------------------------------------------
template <int MODE, int NCOLS>
__global__ void gemm_kernel(const unsigned short* __restrict__ A,
                            const unsigned short* __restrict__ Bt,
                            const float* __restrict__ bias,
                            const f32x2* __restrict__ rope_t,
                            unsigned short* __restrict__ q_out,
                            unsigned short* __restrict__ k_out,
                            unsigned short* __restrict__ v_out,
                            float* __restrict__ f_out)
{
    __shared__ unsigned short SM[2 * 128 * 64];   // As | Bs ; reused as Tv
    unsigned short* As = SM;
    unsigned short* Bs = SM + 128 * 64;

    const int tid  = threadIdx.x;
    const int lane = tid & 63, wid = tid >> 6;
    const int wr = wid >> 1, wc = wid & 1;
    const int lrow = lane & 15, lk = lane >> 4;

    // L2-locality mapping: xcd owns 8 m-tiles x all n-tiles.
    const int xcd = blockIdx.x & 7, loc = blockIdx.x >> 3;
    const int m0 = (xcd * 8 + (loc & 7)) * 128;
    const int n0 = (loc >> 3) * 128;

    f32x4 acc[4][4] = {};

    for (int kt = 0; kt < Kc / 64; ++kt) {
        const int k0 = kt * 64;
        #pragma unroll
        for (int i = 0; i < 4; ++i) {
            const int s   = ((i * 4 + wid) << 6) + lane;
            const int row = s >> 3;
            const int gc  = (s & 7) ^ (row & 7);
            gload16(A  + (size_t)(m0 + row) * Kc + k0 + gc * 8, &As[(i * 4 + wid) << 9]);
            gload16(Bt + (size_t)(n0 + row) * Kc + k0 + gc * 8, &Bs[(i * 4 + wid) << 9]);
        }
        __syncthreads();

        #pragma unroll
        for (int kk = 0; kk < 2; ++kk) {
            bf16x8 a[4], b[4];
            #pragma unroll
            for (int mt = 0; mt < 4; ++mt) {
                const int ra = wr * 64 + mt * 16 + lrow;
                a[mt] = __builtin_bit_cast(bf16x8,
                    *reinterpret_cast<const u16x8*>(&As[ra * 64 + (((kk * 4 + lk) ^ (ra & 7)) << 3)]));
            }
            #pragma unroll
            for (int nt = 0; nt < 4; ++nt) {
                const int rb = wc * 64 + nt * 16 + lrow;
                b[nt] = __builtin_bit_cast(bf16x8,
                    *reinterpret_cast<const u16x8*>(&Bs[rb * 64 + (((kk * 4 + lk) ^ (rb & 7)) << 3)]));
            }
            #pragma unroll
            for (int mt = 0; mt < 4; ++mt)
                #pragma unroll
                for (int nt = 0; nt < 4; ++nt)
                    acc[mt][nt] = __builtin_amdgcn_mfma_f32_16x16x32_bf16(a[mt], b[nt], acc[mt][nt], 0, 0, 0);
        }
        __syncthreads();
    }

    // ---- epilogue ----
    if constexpr (MODE == 1) {
        #pragma unroll
        for (int mt = 0; mt < 4; ++mt)
            #pragma unroll
            for (int nt = 0; nt < 4; ++nt)
                #pragma unroll
                for (int r = 0; r < 4; ++r) {
                    int grow = m0 + wr * 64 + mt * 16 + lk * 4 + r;
                    int gcol = n0 + wc * 64 + nt * 16 + lrow;
                    f_out[(size_t)grow * Cc + gcol] = acc[mt][nt][r] + bias[gcol];
                }
    } else if (n0 >= 2 * Cc) {
        // ---- V: transpose via LDS (stride 136, 16B-aligned rows), 2 passes
        unsigned short* Tv = SM;                  // 64 x 136 u16 = 17.4 KB
        const int bb = m0 >> 11, t0 = m0 & (Tc - 1);
        #pragma unroll
        for (int p = 0; p < 2; ++p) {
            if (wc == p) {
                #pragma unroll
                for (int mt = 0; mt < 4; ++mt)
                    #pragma unroll
                    for (int nt = 0; nt < 4; ++nt)
                        #pragma unroll
                        for (int r = 0; r < 4; ++r) {
                            int hs_l = nt * 16 + lrow;
                            int t_l  = wr * 64 + mt * 16 + lk * 4 + r;
                            int gcol = n0 + wc * 64 + nt * 16 + lrow;
                            Tv[hs_l * 136 + t_l] = f2bf(acc[mt][nt][r] + bias[gcol]);
                        }
            }
            __syncthreads();
            const int h  = ((n0 - 2 * Cc) >> 6) + p;     // head 0..15
            const int bh = bb * Hc + h;
            #pragma unroll
            for (int i = 0; i < 4; ++i) {
                int ch = i * 256 + tid;                  // 0..1023 chunks of 8
                int hs = ch >> 4, tc = ch & 15;
                u16x8 v = *reinterpret_cast<const u16x8*>(&Tv[hs * 136 + tc * 8]);
                *reinterpret_cast<u16x8*>(
                    &v_out[((size_t)bh * HSc + hs) * Tc + t0 + tc * 8]) = v;
            }
            __syncthreads();
        }
    } else {
        // ---- Q/K: fused table-RoPE scatter; Q pre-scaled by 0.125*log2(e)
        const bool isQ = (n0 < Cc);
        unsigned short* dst = isQ ? q_out : k_out;
        const float oscale = isQ ? 0.18033688011112042f : 1.0f;
        #pragma unroll
        for (int mt = 0; mt < 4; ++mt)
            #pragma unroll
            for (int nt = 0; nt < 4; ++nt)
                #pragma unroll
                for (int r = 0; r < 4; ++r) {
                    int grow = m0 + wr * 64 + mt * 16 + lk * 4 + r;
                    int gcol = n0 + wc * 64 + nt * 16 + lrow;
                    float val = acc[mt][nt][r] + bias[gcol];
                    int cc   = gcol & (Cc - 1);
                    int h    = cc >> 6, hs = cc & 63;
                    int bb   = grow >> 11, t = grow & (Tc - 1);
                    int bh   = bb * Hc + h;
                    float partner = __shfl_xor(val, 1, 64);
                    const bool ev = !(lrow & 1);
                    float x1 = ev ? val : partner;
                    float x2 = ev ? partner : val;
                    int d = hs >> 1;
                    f32x2 cs = rope_t[t * 32 + d];
                    float o = ev ? (x1 * cs[0] - x2 * cs[1])
                                 : (x1 * cs[1] + x2 * cs[0]);
                    int hs_out = ev ? d : d + 32;
                    dst[((size_t)bh * Tc + t) * HSc + hs_out] = f2bf(o * oscale);
                }
    }
}

// ---------------------------------------------------------------------------
// Causal flash attention v8 (R14 proven best): wave = 32 q-rows, block = 128,
// grid 1024 XCD-local LPT, dbuf K/V + counted vmcnt(4), no running max
// (Q pre-scaled), diagonal-only masking, 32-row P buffer with ONE lgkm drain,
// deferred row-sum. LDS 51.2 KB -> 3 blocks/CU.
// ---------------------------------------------------------------------------
__launch_bounds__(256, 3)
__global__ void attn_kernel(const unsigned short* __restrict__ Q,
                            const unsigned short* __restrict__ K,
                            const unsigned short* __restrict__ Vt,
                            unsigned short* __restrict__ O)
{
    constexpr int PST = 72;
    __shared__ unsigned short Ks[2][64 * 64];
    __shared__ unsigned short Vs[2][64 * 64];
    __shared__ unsigned short Pl[4 * 32 * PST];   // 32 P-rows per wave

    const int tid = threadIdx.x, lane = tid & 63, wid = tid >> 6;
    const int lrow = lane & 15, lk = lane >> 4;

    const int xcd = blockIdx.x & 7, loc = blockIdx.x >> 3;
    const int bh  = xcd * 8 + (loc & 7);
    const int qs  = 15 - (loc >> 3);
    const int b = bh >> 4, h = bh & 15;

    const unsigned short* Qb = Q  + (size_t)bh * Tc  * HSc;
    const unsigned short* Kb = K  + (size_t)bh * Tc  * HSc;
    const unsigned short* Vb = Vt + (size_t)bh * HSc * Tc;
    unsigned short* pl = &Pl[wid * 32 * PST];

    auto stage = [&](int buf, int kt) {
        const int kv0 = kt * 64;
        #pragma unroll
        for (int rr = 0; rr < 2; ++rr) {
            const int s   = ((rr * 4 + wid) << 6) + lane;
            const int row = s >> 3;
            const int gc  = (s & 7) ^ (row & 7);
            gload16(Kb + (size_t)(kv0 + row) * HSc + gc * 8, &Ks[buf][(rr * 4 + wid) << 9]);
            gload16(Vb + (size_t)row * Tc + kv0 + gc * 8,    &Vs[buf][(rr * 4 + wid) << 9]);
        }
    };

    const int wq0 = qs * 128 + wid * 32;
    const int ntile = 2 * qs + 2;

    bf16x8 qf[2][2];
    #pragma unroll
    for (int f = 0; f < 2; ++f)
        #pragma unroll
        for (int ks = 0; ks < 2; ++ks)
            qf[f][ks] = __builtin_bit_cast(bf16x8,
                *reinterpret_cast<const u16x8*>(Qb + (size_t)(wq0 + f * 16 + lrow) * HSc + ks * 32 + lk * 8));

    f32x4 Oacc[2][4] = {};
    float lsum[2][4] = {};

    stage(0, 0);
    for (int kt = 0; kt < ntile; ++kt) {
        const int kv0 = kt * 64;
        const int cur = kt & 1;
        const bool pre = (kt + 1 < ntile);
        if (pre) stage(cur ^ 1, kt + 1);
        if (pre) asm volatile("s_waitcnt vmcnt(4)" ::: "memory");
        else     asm volatile("s_waitcnt vmcnt(0)" ::: "memory");
        __builtin_amdgcn_s_barrier();

        if (kv0 <= wq0 + 31) {
            f32x4 S[2][4] = {};
            #pragma unroll
            for (int ct = 0; ct < 4; ++ct) {
                const int ro = ct * 16 + lrow;
                bf16x8 kf[2];
                #pragma unroll
                for (int ks = 0; ks < 2; ++ks)
                    kf[ks] = __builtin_bit_cast(bf16x8,
                        *reinterpret_cast<const u16x8*>(&Ks[cur][ro * 64 + (((ks * 4 + lk) ^ (ro & 7)) << 3)]));
                #pragma unroll
                for (int f = 0; f < 2; ++f)
                    #pragma unroll
                    for (int ks = 0; ks < 2; ++ks)
                        S[f][ct] = __builtin_amdgcn_mfma_f32_16x16x32_bf16(qf[f][ks], kf[ks], S[f][ct], 0, 0, 0);
            }

            // ---- P = exp2(S) (S pre-scaled); mask only on diagonal tiles
            #pragma unroll
            for (int f = 0; f < 2; ++f) {
                const bool mf = (kv0 + 63 > wq0 + f * 16);   // wave-uniform
                if (mf) {
                    #pragma unroll
                    for (int ct = 0; ct < 4; ++ct)
                        #pragma unroll
                        for (int r = 0; r < 4; ++r) {
                            float s = S[f][ct][r];
                            if (kv0 + ct * 16 + lrow > wq0 + f * 16 + lk * 4 + r) s = -1e30f;
                            float pv = __builtin_amdgcn_exp2f(s);
                            lsum[f][r] += pv;
                            pl[(f * 16 + lk * 4 + r) * PST + ct * 16 + lrow] =
                                __builtin_bit_cast(unsigned short, (__bf16)pv);
                        }
                } else {
                    #pragma unroll
                    for (int ct = 0; ct < 4; ++ct)
                        #pragma unroll
                        for (int r = 0; r < 4; ++r) {
                            float pv = __builtin_amdgcn_exp2f(S[f][ct][r]);
                            lsum[f][r] += pv;
                            pl[(f * 16 + lk * 4 + r) * PST + ct * 16 + lrow] =
                                __builtin_bit_cast(unsigned short, (__bf16)pv);
                        }
                }
            }
            asm volatile("s_waitcnt lgkmcnt(0)" ::: "memory");
            __builtin_amdgcn_sched_barrier(0);
            bf16x8 pf[2][2];
            #pragma unroll
            for (int f = 0; f < 2; ++f)
                #pragma unroll
                for (int ks = 0; ks < 2; ++ks)
                    pf[f][ks] = __builtin_bit_cast(bf16x8,
                        *reinterpret_cast<const u16x8*>(&pl[(f * 16 + lrow) * PST + ks * 32 + lk * 8]));

            #pragma unroll
            for (int nt = 0; nt < 4; ++nt) {
                const int ro = nt * 16 + lrow;
                bf16x8 vf[2];
                #pragma unroll
                for (int ks = 0; ks < 2; ++ks)
                    vf[ks] = __builtin_bit_cast(bf16x8,
                        *reinterpret_cast<const u16x8*>(&Vs[cur][ro * 64 + (((ks * 4 + lk) ^ (ro & 7)) << 3)]));
                #pragma unroll
                for (int f = 0; f < 2; ++f)
                    #pragma unroll
                    for (int ks = 0; ks < 2; ++ks)
                        Oacc[f][nt] = __builtin_amdgcn_mfma_f32_16x16x32_bf16(pf[f][ks], vf[ks], Oacc[f][nt], 0, 0, 0);
            }
        }
        asm volatile("s_waitcnt lgkmcnt(0)" ::: "memory");   // all LDS reads landed
        __builtin_amdgcn_sched_barrier(0);
        __builtin_amdgcn_s_barrier();         // safe to overwrite bufs
    }

    #pragma unroll
    for (int f = 0; f < 2; ++f) {
        #pragma unroll
        for (int mk = 1; mk < 16; mk <<= 1)
            #pragma unroll
            for (int r = 0; r < 4; ++r) lsum[f][r] += __shfl_xor(lsum[f][r], mk, 64);
        #pragma unroll
        for (int r = 0; r < 4; ++r) {
            float inv = 1.0f / lsum[f][r];
            int t = wq0 + f * 16 + lk * 4 + r;
            #pragma unroll
            for (int nt = 0; nt < 4; ++nt) {
                int col = h * 64 + nt * 16 + lrow;
                O[((size_t)b * Tc + t) * Cc + col] = f2bf(Oacc[f][nt][r] * inv);
            }
        }
    }
}

// ---------------------------------------------------------------------------
extern "C" void kernel_launch(void* const* d_in, const int* in_sizes, int n_in,
                              void* d_out, int out_size, void* d_ws, size_t ws_size,
                              hipStream_t stream)
{
    const float* x    = (const float*)d_in[0];
    const float* Wqkv = (const float*)d_in[1];
    const float* bqkv = (const float*)d_in[2];
    const float* Wo   = (const float*)d_in[3];
    const float* bo   = (const float*)d_in[4];
    float* out = (float*)d_out;

    char* ws = (char*)d_ws;
    size_t off = 0;
    auto alloc = [&](size_t bytes) {
        void* p = ws + off;
        off += (bytes + 255) & ~(size_t)255;
        return p;
    };
    const size_t elems = (size_t)Bc * Hc * Tc * HSc;          // 8.4M
    unsigned short* Qb  = (unsigned short*)alloc(elems * 2);
    unsigned short* Kb  = (unsigned short*)alloc(elems * 2);
    unsigned short* Vt  = (unsigned short*)alloc(elems * 2);
    unsigned short* Oa  = (unsigned short*)alloc(elems * 2);
    unsigned short* Xb  = (unsigned short*)alloc((size_t)Mc * Kc * 2);      // x bf16
    unsigned short* Wq_t = (unsigned short*)alloc((size_t)N1c * Kc * 2);    // Wqkv^T bf16
    unsigned short* Wo_t = (unsigned short*)alloc((size_t)Cc * Kc * 2);     // Wo^T bf16
    f32x2* Rt = (f32x2*)alloc((size_t)Tc * 32 * 8);                          // rope table

    // Prep (2 fused launches): rope table + x cvt; both W transposes
    prep_kernel<<<256 + (Mc * Kc) / (256 * 8), 256, 0, stream>>>(x, Xb, Rt);
    wt2_kernel<<<768 + 256, 256, 0, stream>>>(Wqkv, Wo, Wq_t, Wo_t);

    // 1) QKV projection + fused table-RoPE (Q pre-scaled) + coalesced-V scatter
    gemm_kernel<0, N1c><<<(N1c / 128) * (Mc / 128), 256, 0, stream>>>(
        Xb, Wq_t, bqkv, Rt, Qb, Kb, Vt, nullptr);
    // 2) causal flash attention (1024 blocks, XCD-local LPT)
    attn_kernel<<<1024, 256, 0, stream>>>(Qb, Kb, Vt, Oa);
    // 3) output projection -> fp32 d_out (grid 512)
    gemm_kernel<1, Cc><<<(Cc / 128) * (Mc / 128), 256, 0, stream>>>(
        Oa, Wo_t, bo, nullptr, nullptr, nullptr, nullptr, out);
}

// Round 18
// 164.984 us; speedup vs baseline: 1.1716x; 1.0014x over previous
//
#include <hip/hip_runtime.h>
#include <math.h>

typedef float  f32x4 __attribute__((ext_vector_type(4)));
typedef float  f32x2 __attribute__((ext_vector_type(2)));
typedef __bf16 bf16x8 __attribute__((ext_vector_type(8)));
typedef unsigned short u16x8 __attribute__((ext_vector_type(8)));

#define DEVI __device__ __forceinline__

constexpr int Bc = 4, Tc = 2048, Cc = 1024, Hc = 16, HSc = 64;
constexpr int Mc  = Bc * Tc;    // 8192 rows
constexpr int N1c = 3 * Cc;     // 3072 qkv cols
constexpr int Kc  = Cc;         // 1024 reduce dim

DEVI unsigned short f2bf(float f) {            // RNE fp32 -> bf16
    unsigned u = __builtin_bit_cast(unsigned, f);
    u += 0x7FFFu + ((u >> 16) & 1u);
    return (unsigned short)(u >> 16);
}

typedef const __attribute__((address_space(1))) void* gbl_vp;
typedef __attribute__((address_space(3))) void* lds_vp;
DEVI void gload16(const unsigned short* g, unsigned short* l) {
    __builtin_amdgcn_global_load_lds((gbl_vp)g, (lds_vp)l, 16, 0, 0);
}

// ---------------------------------------------------------------------------
// Prep (single fused launch):
//   blocks [0,256)        -> RoPE table
//   blocks [256,4352)     -> x fp32 -> bf16
//   blocks [4352,5120)    -> Wqkv transpose (48x16 64x64 tiles)
//   blocks [5120,5376)    -> Wo transpose (16x16 tiles)
// ---------------------------------------------------------------------------
__global__ void prep_kernel(const float* __restrict__ x,
                            const float* __restrict__ Wq,
                            const float* __restrict__ Wo,
                            unsigned short* __restrict__ Xb,
                            unsigned short* __restrict__ Wq_t,
                            unsigned short* __restrict__ Wo_t,
                            f32x2* __restrict__ tab)
{
    const int bid = blockIdx.x;
    const int tid = threadIdx.x;
    if (bid < 256) {
        const int i = bid * 256 + tid;           // 0 .. 2048*32
        const int t = i >> 5, d = i & 31;
        float theta = exp2f(-(float)d * 0.41524101186186f);  // 10000^(-d/32)
        float s, c;
        sincosf((float)t * theta, &s, &c);
        f32x2 v; v[0] = c; v[1] = s;
        tab[i] = v;
        return;
    }
    if (bid < 4352) {
        const size_t i = ((size_t)(bid - 256) * 256 + tid) * 8;
        f32x4 a = *reinterpret_cast<const f32x4*>(x + i);
        f32x4 b = *reinterpret_cast<const f32x4*>(x + i + 4);
        u16x8 o;
        o[0] = f2bf(a[0]); o[1] = f2bf(a[1]); o[2] = f2bf(a[2]); o[3] = f2bf(a[3]);
        o[4] = f2bf(b[0]); o[5] = f2bf(b[1]); o[6] = f2bf(b[2]); o[7] = f2bf(b[3]);
        *reinterpret_cast<u16x8*>(Xb + i) = o;
        return;
    }
    // ---- W transposes ----
    __shared__ unsigned short Ts[64][72];
    int wb = bid - 4352;
    const float* W; unsigned short* Wt; int N, bx, by;
    if (wb < 768) { W = Wq; Wt = Wq_t; N = N1c; bx = wb % 48; by = wb / 48; }
    else { wb -= 768; W = Wo; Wt = Wo_t; N = Cc; bx = wb % 16; by = wb / 16; }
    const int n0 = bx * 64, k0 = by * 64;

    #pragma unroll
    for (int i = 0; i < 4; ++i) {
        int kr = (tid >> 4) + i * 16, nc = (tid & 15) * 4;
        f32x4 v = *reinterpret_cast<const f32x4*>(W + (size_t)(k0 + kr) * N + n0 + nc);
        #pragma unroll
        for (int e = 0; e < 4; ++e) Ts[kr][nc + e] = f2bf(v[e]);
    }
    __syncthreads();
    #pragma unroll
    for (int i = 0; i < 2; ++i) {
        int s = tid * 2 + i;
        int n = s >> 3, k8 = (s & 7) * 8;
        u16x8 o;
        #pragma unroll
        for (int j = 0; j < 8; ++j) o[j] = Ts[k8 + j][n];
        *reinterpret_cast<u16x8*>(Wt + (size_t)(n0 + n) * Kc + k0 + k8) = o;
    }
}

// ---------------------------------------------------------------------------
// bf16 GEMM (R14 proven): C = A @ Bt^T + bias
// 128x128 tile, BK=64, 256 thr = 4 waves; global_load_lds w=16 staging,
// pre-swizzled source + XOR ds_read (0 conflicts), XCD m-slice L2 mapping.
// MODE 0: Q -> RoPE * softmax-scale; K -> RoPE; V -> LDS-transposed
//         coalesced 16B stores.
// MODE 1: fp32 + bias to f_out.
// ---------------------------------------------------------------------------
template <int MODE, int NCOLS>
__global__ void gemm_kernel(const unsigned short* __restrict__ A,
                            const unsigned short* __restrict__ Bt,
                            const float* __restrict__ bias,
                            const f32x2* __restrict__ rope_t,
                            unsigned short* __restrict__ q_out,
                            unsigned short* __restrict__ k_out,
                            unsigned short* __restrict__ v_out,
                            float* __restrict__ f_out)
{
    __shared__ unsigned short SM[2 * 128 * 64];   // As | Bs ; reused as Tv
    unsigned short* As = SM;
    unsigned short* Bs = SM + 128 * 64;

    const int tid  = threadIdx.x;
    const int lane = tid & 63, wid = tid >> 6;
    const int wr = wid >> 1, wc = wid & 1;
    const int lrow = lane & 15, lk = lane >> 4;

    // L2-locality mapping: xcd owns 8 m-tiles x all n-tiles.
    const int xcd = blockIdx.x & 7, loc = blockIdx.x >> 3;
    const int m0 = (xcd * 8 + (loc & 7)) * 128;
    const int n0 = (loc >> 3) * 128;

    f32x4 acc[4][4] = {};

    for (int kt = 0; kt < Kc / 64; ++kt) {
        const int k0 = kt * 64;
        #pragma unroll
        for (int i = 0; i < 4; ++i) {
            const int s   = ((i * 4 + wid) << 6) + lane;
            const int row = s >> 3;
            const int gc  = (s & 7) ^ (row & 7);
            gload16(A  + (size_t)(m0 + row) * Kc + k0 + gc * 8, &As[(i * 4 + wid) << 9]);
            gload16(Bt + (size_t)(n0 + row) * Kc + k0 + gc * 8, &Bs[(i * 4 + wid) << 9]);
        }
        __syncthreads();

        #pragma unroll
        for (int kk = 0; kk < 2; ++kk) {
            bf16x8 a[4], b[4];
            #pragma unroll
            for (int mt = 0; mt < 4; ++mt) {
                const int ra = wr * 64 + mt * 16 + lrow;
                a[mt] = __builtin_bit_cast(bf16x8,
                    *reinterpret_cast<const u16x8*>(&As[ra * 64 + (((kk * 4 + lk) ^ (ra & 7)) << 3)]));
            }
            #pragma unroll
            for (int nt = 0; nt < 4; ++nt) {
                const int rb = wc * 64 + nt * 16 + lrow;
                b[nt] = __builtin_bit_cast(bf16x8,
                    *reinterpret_cast<const u16x8*>(&Bs[rb * 64 + (((kk * 4 + lk) ^ (rb & 7)) << 3)]));
            }
            #pragma unroll
            for (int mt = 0; mt < 4; ++mt)
                #pragma unroll
                for (int nt = 0; nt < 4; ++nt)
                    acc[mt][nt] = __builtin_amdgcn_mfma_f32_16x16x32_bf16(a[mt], b[nt], acc[mt][nt], 0, 0, 0);
        }
        __syncthreads();
    }

    // ---- epilogue ----
    if constexpr (MODE == 1) {
        #pragma unroll
        for (int mt = 0; mt < 4; ++mt)
            #pragma unroll
            for (int nt = 0; nt < 4; ++nt)
                #pragma unroll
                for (int r = 0; r < 4; ++r) {
                    int grow = m0 + wr * 64 + mt * 16 + lk * 4 + r;
                    int gcol = n0 + wc * 64 + nt * 16 + lrow;
                    f_out[(size_t)grow * Cc + gcol] = acc[mt][nt][r] + bias[gcol];
                }
    } else if (n0 >= 2 * Cc) {
        // ---- V: transpose via LDS (stride 136, 16B-aligned rows), 2 passes
        unsigned short* Tv = SM;                  // 64 x 136 u16 = 17.4 KB
        const int bb = m0 >> 11, t0 = m0 & (Tc - 1);
        #pragma unroll
        for (int p = 0; p < 2; ++p) {
            if (wc == p) {
                #pragma unroll
                for (int mt = 0; mt < 4; ++mt)
                    #pragma unroll
                    for (int nt = 0; nt < 4; ++nt)
                        #pragma unroll
                        for (int r = 0; r < 4; ++r) {
                            int hs_l = nt * 16 + lrow;
                            int t_l  = wr * 64 + mt * 16 + lk * 4 + r;
                            int gcol = n0 + wc * 64 + nt * 16 + lrow;
                            Tv[hs_l * 136 + t_l] = f2bf(acc[mt][nt][r] + bias[gcol]);
                        }
            }
            __syncthreads();
            const int h  = ((n0 - 2 * Cc) >> 6) + p;     // head 0..15
            const int bh = bb * Hc + h;
            #pragma unroll
            for (int i = 0; i < 4; ++i) {
                int ch = i * 256 + tid;                  // 0..1023 chunks of 8
                int hs = ch >> 4, tc = ch & 15;
                u16x8 v = *reinterpret_cast<const u16x8*>(&Tv[hs * 136 + tc * 8]);
                *reinterpret_cast<u16x8*>(
                    &v_out[((size_t)bh * HSc + hs) * Tc + t0 + tc * 8]) = v;
            }
            __syncthreads();
        }
    } else {
        // ---- Q/K: fused table-RoPE scatter; Q pre-scaled by 0.125*log2(e)
        const bool isQ = (n0 < Cc);
        unsigned short* dst = isQ ? q_out : k_out;
        const float oscale = isQ ? 0.18033688011112042f : 1.0f;
        #pragma unroll
        for (int mt = 0; mt < 4; ++mt)
            #pragma unroll
            for (int nt = 0; nt < 4; ++nt)
                #pragma unroll
                for (int r = 0; r < 4; ++r) {
                    int grow = m0 + wr * 64 + mt * 16 + lk * 4 + r;
                    int gcol = n0 + wc * 64 + nt * 16 + lrow;
                    float val = acc[mt][nt][r] + bias[gcol];
                    int cc   = gcol & (Cc - 1);
                    int h    = cc >> 6, hs = cc & 63;
                    int bb   = grow >> 11, t = grow & (Tc - 1);
                    int bh   = bb * Hc + h;
                    float partner = __shfl_xor(val, 1, 64);
                    const bool ev = !(lrow & 1);
                    float x1 = ev ? val : partner;
                    float x2 = ev ? partner : val;
                    int d = hs >> 1;
                    f32x2 cs = rope_t[t * 32 + d];
                    float o = ev ? (x1 * cs[0] - x2 * cs[1])
                                 : (x1 * cs[1] + x2 * cs[0]);
                    int hs_out = ev ? d : d + 32;
                    dst[((size_t)bh * Tc + t) * HSc + hs_out] = f2bf(o * oscale);
                }
    }
}

// ---------------------------------------------------------------------------
// Causal flash attention v8.1: R14 v8 + V-fragment reads hoisted ABOVE the
// P drain (V depends only on the staging barrier; the single lgkmcnt(0)
// then covers P-writes and V-reads together, taking the 8 b128 V reads off
// the post-drain critical path).
// ---------------------------------------------------------------------------
__launch_bounds__(256, 3)
__global__ void attn_kernel(const unsigned short* __restrict__ Q,
                            const unsigned short* __restrict__ K,
                            const unsigned short* __restrict__ Vt,
                            unsigned short* __restrict__ O)
{
    constexpr int PST = 72;
    __shared__ unsigned short Ks[2][64 * 64];
    __shared__ unsigned short Vs[2][64 * 64];
    __shared__ unsigned short Pl[4 * 32 * PST];   // 32 P-rows per wave

    const int tid = threadIdx.x, lane = tid & 63, wid = tid >> 6;
    const int lrow = lane & 15, lk = lane >> 4;

    const int xcd = blockIdx.x & 7, loc = blockIdx.x >> 3;
    const int bh  = xcd * 8 + (loc & 7);
    const int qs  = 15 - (loc >> 3);
    const int b = bh >> 4, h = bh & 15;

    const unsigned short* Qb = Q  + (size_t)bh * Tc  * HSc;
    const unsigned short* Kb = K  + (size_t)bh * Tc  * HSc;
    const unsigned short* Vb = Vt + (size_t)bh * HSc * Tc;
    unsigned short* pl = &Pl[wid * 32 * PST];

    auto stage = [&](int buf, int kt) {
        const int kv0 = kt * 64;
        #pragma unroll
        for (int rr = 0; rr < 2; ++rr) {
            const int s   = ((rr * 4 + wid) << 6) + lane;
            const int row = s >> 3;
            const int gc  = (s & 7) ^ (row & 7);
            gload16(Kb + (size_t)(kv0 + row) * HSc + gc * 8, &Ks[buf][(rr * 4 + wid) << 9]);
            gload16(Vb + (size_t)row * Tc + kv0 + gc * 8,    &Vs[buf][(rr * 4 + wid) << 9]);
        }
    };

    const int wq0 = qs * 128 + wid * 32;
    const int ntile = 2 * qs + 2;

    bf16x8 qf[2][2];
    #pragma unroll
    for (int f = 0; f < 2; ++f)
        #pragma unroll
        for (int ks = 0; ks < 2; ++ks)
            qf[f][ks] = __builtin_bit_cast(bf16x8,
                *reinterpret_cast<const u16x8*>(Qb + (size_t)(wq0 + f * 16 + lrow) * HSc + ks * 32 + lk * 8));

    f32x4 Oacc[2][4] = {};
    float lsum[2][4] = {};

    stage(0, 0);
    for (int kt = 0; kt < ntile; ++kt) {
        const int kv0 = kt * 64;
        const int cur = kt & 1;
        const bool pre = (kt + 1 < ntile);
        if (pre) stage(cur ^ 1, kt + 1);
        if (pre) asm volatile("s_waitcnt vmcnt(4)" ::: "memory");
        else     asm volatile("s_waitcnt vmcnt(0)" ::: "memory");
        __builtin_amdgcn_s_barrier();

        if (kv0 <= wq0 + 31) {
            f32x4 S[2][4] = {};
            #pragma unroll
            for (int ct = 0; ct < 4; ++ct) {
                const int ro = ct * 16 + lrow;
                bf16x8 kf[2];
                #pragma unroll
                for (int ks = 0; ks < 2; ++ks)
                    kf[ks] = __builtin_bit_cast(bf16x8,
                        *reinterpret_cast<const u16x8*>(&Ks[cur][ro * 64 + (((ks * 4 + lk) ^ (ro & 7)) << 3)]));
                #pragma unroll
                for (int f = 0; f < 2; ++f)
                    #pragma unroll
                    for (int ks = 0; ks < 2; ++ks)
                        S[f][ct] = __builtin_amdgcn_mfma_f32_16x16x32_bf16(qf[f][ks], kf[ks], S[f][ct], 0, 0, 0);
            }

            // ---- P = exp2(S) (S pre-scaled); mask only on diagonal tiles
            #pragma unroll
            for (int f = 0; f < 2; ++f) {
                const bool mf = (kv0 + 63 > wq0 + f * 16);   // wave-uniform
                if (mf) {
                    #pragma unroll
                    for (int ct = 0; ct < 4; ++ct)
                        #pragma unroll
                        for (int r = 0; r < 4; ++r) {
                            float s = S[f][ct][r];
                            if (kv0 + ct * 16 + lrow > wq0 + f * 16 + lk * 4 + r) s = -1e30f;
                            float pv = __builtin_amdgcn_exp2f(s);
                            lsum[f][r] += pv;
                            pl[(f * 16 + lk * 4 + r) * PST + ct * 16 + lrow] =
                                __builtin_bit_cast(unsigned short, (__bf16)pv);
                        }
                } else {
                    #pragma unroll
                    for (int ct = 0; ct < 4; ++ct)
                        #pragma unroll
                        for (int r = 0; r < 4; ++r) {
                            float pv = __builtin_amdgcn_exp2f(S[f][ct][r]);
                            lsum[f][r] += pv;
                            pl[(f * 16 + lk * 4 + r) * PST + ct * 16 + lrow] =
                                __builtin_bit_cast(unsigned short, (__bf16)pv);
                        }
                }
            }

            // ---- V-frag reads issued BEFORE the drain (independent of P)
            bf16x8 vf[4][2];
            #pragma unroll
            for (int nt = 0; nt < 4; ++nt) {
                const int ro = nt * 16 + lrow;
                #pragma unroll
                for (int ks = 0; ks < 2; ++ks)
                    vf[nt][ks] = __builtin_bit_cast(bf16x8,
                        *reinterpret_cast<const u16x8*>(&Vs[cur][ro * 64 + (((ks * 4 + lk) ^ (ro & 7)) << 3)]));
            }
            asm volatile("s_waitcnt lgkmcnt(0)" ::: "memory");   // P-writes + V-reads
            __builtin_amdgcn_sched_barrier(0);
            bf16x8 pf[2][2];
            #pragma unroll
            for (int f = 0; f < 2; ++f)
                #pragma unroll
                for (int ks = 0; ks < 2; ++ks)
                    pf[f][ks] = __builtin_bit_cast(bf16x8,
                        *reinterpret_cast<const u16x8*>(&pl[(f * 16 + lrow) * PST + ks * 32 + lk * 8]));

            #pragma unroll
            for (int nt = 0; nt < 4; ++nt)
                #pragma unroll
                for (int f = 0; f < 2; ++f)
                    #pragma unroll
                    for (int ks = 0; ks < 2; ++ks)
                        Oacc[f][nt] = __builtin_amdgcn_mfma_f32_16x16x32_bf16(pf[f][ks], vf[nt][ks], Oacc[f][nt], 0, 0, 0);
        }
        asm volatile("s_waitcnt lgkmcnt(0)" ::: "memory");   // all LDS reads landed
        __builtin_amdgcn_sched_barrier(0);
        __builtin_amdgcn_s_barrier();         // safe to overwrite bufs
    }

    #pragma unroll
    for (int f = 0; f < 2; ++f) {
        #pragma unroll
        for (int mk = 1; mk < 16; mk <<= 1)
            #pragma unroll
            for (int r = 0; r < 4; ++r) lsum[f][r] += __shfl_xor(lsum[f][r], mk, 64);
        #pragma unroll
        for (int r = 0; r < 4; ++r) {
            float inv = 1.0f / lsum[f][r];
            int t = wq0 + f * 16 + lk * 4 + r;
            #pragma unroll
            for (int nt = 0; nt < 4; ++nt) {
                int col = h * 64 + nt * 16 + lrow;
                O[((size_t)b * Tc + t) * Cc + col] = f2bf(Oacc[f][nt][r] * inv);
            }
        }
    }
}

// ---------------------------------------------------------------------------
extern "C" void kernel_launch(void* const* d_in, const int* in_sizes, int n_in,
                              void* d_out, int out_size, void* d_ws, size_t ws_size,
                              hipStream_t stream)
{
    const float* x    = (const float*)d_in[0];
    const float* Wqkv = (const float*)d_in[1];
    const float* bqkv = (const float*)d_in[2];
    const float* Wo   = (const float*)d_in[3];
    const float* bo   = (const float*)d_in[4];
    float* out = (float*)d_out;

    char* ws = (char*)d_ws;
    size_t off = 0;
    auto alloc = [&](size_t bytes) {
        void* p = ws + off;
        off += (bytes + 255) & ~(size_t)255;
        return p;
    };
    const size_t elems = (size_t)Bc * Hc * Tc * HSc;          // 8.4M
    unsigned short* Qb  = (unsigned short*)alloc(elems * 2);
    unsigned short* Kb  = (unsigned short*)alloc(elems * 2);
    unsigned short* Vt  = (unsigned short*)alloc(elems * 2);
    unsigned short* Oa  = (unsigned short*)alloc(elems * 2);
    unsigned short* Xb  = (unsigned short*)alloc((size_t)Mc * Kc * 2);      // x bf16
    unsigned short* Wq_t = (unsigned short*)alloc((size_t)N1c * Kc * 2);    // Wqkv^T bf16
    unsigned short* Wo_t = (unsigned short*)alloc((size_t)Cc * Kc * 2);     // Wo^T bf16
    f32x2* Rt = (f32x2*)alloc((size_t)Tc * 32 * 8);                          // rope table

    // Prep (single fused launch): rope table + x cvt + both W transposes
    prep_kernel<<<256 + (Mc * Kc) / (256 * 8) + 768 + 256, 256, 0, stream>>>(
        x, Wqkv, Wo, Xb, Wq_t, Wo_t, Rt);

    // 1) QKV projection + fused table-RoPE (Q pre-scaled) + coalesced-V scatter
    gemm_kernel<0, N1c><<<(N1c / 128) * (Mc / 128), 256, 0, stream>>>(
        Xb, Wq_t, bqkv, Rt, Qb, Kb, Vt, nullptr);
    // 2) causal flash attention (1024 blocks, XCD-local LPT)
    attn_kernel<<<1024, 256, 0, stream>>>(Qb, Kb, Vt, Oa);
    // 3) output projection -> fp32 d_out (grid 512)
    gemm_kernel<1, Cc><<<(Cc / 128) * (Mc / 128), 256, 0, stream>>>(
        Oa, Wo_t, bo, nullptr, nullptr, nullptr, nullptr, out);
}